// Round 4
// baseline (298.655 us; speedup 1.0000x reference)
//
#include <hip/hip_runtime.h>
#include <hip/hip_bf16.h>

#define BATCH 2
#define SEQ 2048
#define HID 1024
#define NHEAD 16
#define HDIM 64
// combined softmax scale: TEMP_K / sqrt(HEAD_DIM) = 1000/8
#define LSCALE 125.0f
#define NEGBIG (-1.0e30f)
#define N_ITEMS 512   // 16 q-tiles x 32 (b,h)

typedef __bf16 bf16;
typedef __bf16 bf16x4 __attribute__((ext_vector_type(4)));
typedef __bf16 bf16x8 __attribute__((ext_vector_type(8)));
typedef float f32x16 __attribute__((ext_vector_type(16)));

// ---------------------------------------------------------------------------
// Prep A: transpose fp32 W[K][N] -> bf16 hi (and optional lo) [N][K].
// ---------------------------------------------------------------------------
__global__ __launch_bounds__(256) void transpose_split_kernel(
    const float* __restrict__ W, bf16* __restrict__ Thi, bf16* __restrict__ Tlo,
    int K, int N)
{
    __shared__ float T[64][65];
    const int tid = threadIdx.x;
    const int kBase = blockIdx.y * 64;
    const int nBase = blockIdx.x * 64;
    {
        const int k0 = tid >> 4;
        const int nc = (tid & 15) * 4;
#pragma unroll
        for (int kk = 0; kk < 4; kk++) {
            int k = k0 + kk * 16;
            float4 v = *(const float4*)(W + (size_t)(kBase + k) * N + nBase + nc);
            T[k][nc] = v.x; T[k][nc + 1] = v.y; T[k][nc + 2] = v.z; T[k][nc + 3] = v.w;
        }
    }
    __syncthreads();
    {
        const int n = tid >> 2;
        const int kc = (tid & 3) * 16;
        bf16x8 h0, h1, l0, l1;
#pragma unroll
        for (int j = 0; j < 8; j++) {
            float a = T[kc + j][n];
            float c = T[kc + 8 + j][n];
            bf16 ha = (bf16)a, hc = (bf16)c;
            h0[j] = ha; h1[j] = hc;
            l0[j] = (bf16)(a - (float)ha);
            l1[j] = (bf16)(c - (float)hc);
        }
        size_t dst = (size_t)(nBase + n) * K + kBase + kc;
        *(bf16x8*)(Thi + dst)     = h0;
        *(bf16x8*)(Thi + dst + 8) = h1;
        if (Tlo) {
            *(bf16x8*)(Tlo + dst)     = l0;
            *(bf16x8*)(Tlo + dst + 8) = l1;
        }
    }
}

// ---------------------------------------------------------------------------
// Prep B: split X fp32 -> Xhi/Xlo bf16 (elementwise). Also zeroes the attn
// work-queue counter (stream-ordered before attn_kernel; ws is re-poisoned
// 0xAA before every launch so this must happen every call).
// ---------------------------------------------------------------------------
__global__ __launch_bounds__(256) void xsplit_kernel(
    const float* __restrict__ X, bf16* __restrict__ Xhi, bf16* __restrict__ Xlo,
    unsigned* __restrict__ ctr)
{
    if (blockIdx.x == 0 && threadIdx.x == 0) *ctr = 0u;
    const int i = blockIdx.x * 256 + threadIdx.x;   // one float4 per thread
    float4 v = ((const float4*)X)[i];
    float xs[4] = {v.x, v.y, v.z, v.w};
    bf16x4 h, l;
#pragma unroll
    for (int j = 0; j < 4; j++) {
        h[j] = (bf16)xs[j];
        l[j] = (bf16)(xs[j] - (float)h[j]);
    }
    ((bf16x4*)Xhi)[i] = h;
    ((bf16x4*)Xlo)[i] = l;
}

// ---------------------------------------------------------------------------
// GEMM1 (MFMA): qkv = x @ W_qkv + b_qkv with pre-split bf16 operands.
// D^T orientation: A = W^T rows [n][k], B = X rows [m][k]; epilogue lane owns
// one sequence row with d-contiguous cols. Q/K cols: 3-pass split-bf16
// (precision under TEMP=1000); V cols (nBase>=2048): plain bf16 hi only.
// LDS pitch 40 bf16: frag b128 reads tile all 32 banks.
// ---------------------------------------------------------------------------
__global__ __launch_bounds__(256) void gemm_qkv_mfma(
    const bf16* __restrict__ Xhi, const bf16* __restrict__ Xlo,
    const bf16* __restrict__ Wthi, const bf16* __restrict__ Wtlo,
    const float* __restrict__ bias,
    bf16* __restrict__ qhi, bf16* __restrict__ qlo,
    bf16* __restrict__ khi, bf16* __restrict__ klo, bf16* __restrict__ vv)
{
    __shared__ __align__(16) bf16 Xh[128][40];
    __shared__ __align__(16) bf16 Xl[128][40];
    __shared__ __align__(16) bf16 Wh[128][40];
    __shared__ __align__(16) bf16 Wl[128][40];

    const int tid = threadIdx.x;
    const int wave = tid >> 6, lane = tid & 63;
    const int lm = lane & 31, lq2 = lane >> 5;
    const int wave_s = wave & 1, wave_n = wave >> 1;
    const int nBase = blockIdx.x * 128;
    const int sBase = blockIdx.y * 128;
    const bool isV = (nBase >= 2 * HID);

    const int sr = tid >> 1, skc = (tid & 1) * 16;  // staging row / k-chunk

    f32x16 acc[2][2];
#pragma unroll
    for (int st = 0; st < 2; st++)
#pragma unroll
      for (int nt = 0; nt < 2; nt++)
#pragma unroll
        for (int r = 0; r < 16; r++) acc[st][nt][r] = 0.f;

    for (int k0 = 0; k0 < HID; k0 += 32) {
        size_t xsrc = (size_t)(sBase + sr) * HID + k0 + skc;
        size_t wsrc = (size_t)(nBase + sr) * HID + k0 + skc;
        bf16x8 xh0 = *(const bf16x8*)(Xhi + xsrc);
        bf16x8 xh1 = *(const bf16x8*)(Xhi + xsrc + 8);
        bf16x8 wh0 = *(const bf16x8*)(Wthi + wsrc);
        bf16x8 wh1 = *(const bf16x8*)(Wthi + wsrc + 8);
        bf16x8 xl0 = {}, xl1 = {}, wl0 = {}, wl1 = {};
        if (!isV) {
            xl0 = *(const bf16x8*)(Xlo + xsrc);
            xl1 = *(const bf16x8*)(Xlo + xsrc + 8);
            wl0 = *(const bf16x8*)(Wtlo + wsrc);
            wl1 = *(const bf16x8*)(Wtlo + wsrc + 8);
        }
        __syncthreads();
        *(bf16x8*)&Xh[sr][skc]     = xh0;
        *(bf16x8*)&Xh[sr][skc + 8] = xh1;
        *(bf16x8*)&Wh[sr][skc]     = wh0;
        *(bf16x8*)&Wh[sr][skc + 8] = wh1;
        if (!isV) {
            *(bf16x8*)&Xl[sr][skc]     = xl0;
            *(bf16x8*)&Xl[sr][skc + 8] = xl1;
            *(bf16x8*)&Wl[sr][skc]     = wl0;
            *(bf16x8*)&Wl[sr][skc + 8] = wl1;
        }
        __syncthreads();

#pragma unroll
        for (int kh = 0; kh < 2; kh++) {
            const int ko = kh * 16 + lq2 * 8;
            bf16x8 aWh[2], aWl[2], bXh[2], bXl[2];
#pragma unroll
            for (int nt = 0; nt < 2; nt++) {
                aWh[nt] = *(bf16x8*)&Wh[wave_n * 64 + nt * 32 + lm][ko];
                if (!isV) aWl[nt] = *(bf16x8*)&Wl[wave_n * 64 + nt * 32 + lm][ko];
            }
#pragma unroll
            for (int st = 0; st < 2; st++) {
                bXh[st] = *(bf16x8*)&Xh[wave_s * 64 + st * 32 + lm][ko];
                if (!isV) bXl[st] = *(bf16x8*)&Xl[wave_s * 64 + st * 32 + lm][ko];
            }
#pragma unroll
            for (int nt = 0; nt < 2; nt++)
#pragma unroll
              for (int st = 0; st < 2; st++) {
                acc[st][nt] = __builtin_amdgcn_mfma_f32_32x32x16_bf16(aWh[nt], bXh[st], acc[st][nt], 0, 0, 0);
                if (!isV) {
                    acc[st][nt] = __builtin_amdgcn_mfma_f32_32x32x16_bf16(aWh[nt], bXl[st], acc[st][nt], 0, 0, 0);
                    acc[st][nt] = __builtin_amdgcn_mfma_f32_32x32x16_bf16(aWl[nt], bXh[st], acc[st][nt], 0, 0, 0);
                }
              }
        }
    }

    // epilogue: lane owns seq-row s (per st); cols n quad-contiguous
#pragma unroll
    for (int st = 0; st < 2; st++) {
        int s = sBase + wave_s * 64 + st * 32 + lm;
        int bb = s >> 11, ss = s & 2047;
#pragma unroll
        for (int nt = 0; nt < 2; nt++) {
#pragma unroll
            for (int q4 = 0; q4 < 4; q4++) {
                int n = nBase + wave_n * 64 + nt * 32 + 8 * q4 + 4 * lq2;
                float4 bv = *(const float4*)(bias + n);
                float vals[4];
                vals[0] = acc[st][nt][q4 * 4 + 0] + bv.x;
                vals[1] = acc[st][nt][q4 * 4 + 1] + bv.y;
                vals[2] = acc[st][nt][q4 * 4 + 2] + bv.z;
                vals[3] = acc[st][nt][q4 * 4 + 3] + bv.w;
                int which = n >> 10, h = (n >> 6) & 15, d = n & 63;
                size_t dst = (((size_t)bb * NHEAD + h) * SEQ + ss) * HDIM + d;
                if (which < 2) {
                    bf16x4 hi4, lo4;
#pragma unroll
                    for (int i = 0; i < 4; i++) {
                        hi4[i] = (bf16)vals[i];
                        lo4[i] = (bf16)(vals[i] - (float)hi4[i]);
                    }
                    bf16* ph = (which == 0) ? qhi : khi;
                    bf16* pl = (which == 0) ? qlo : klo;
                    *(bf16x4*)(ph + dst) = hi4;
                    *(bf16x4*)(pl + dst) = lo4;
                } else {
                    bf16x4 v4;
#pragma unroll
                    for (int i = 0; i < 4; i++) v4[i] = (bf16)vals[i];
                    *(bf16x4*)(vv + dst) = v4;
                }
            }
        }
    }
}

// ---------------------------------------------------------------------------
// MFMA flash attention — PERSISTENT blocks + device-scope atomic work queue.
// 768 blocks (3/CU, LDS-capped); items (qt, bh) pulled heavy-first, so the
// triangular imbalance load-balances regardless of workgroup->CU placement.
// Per item: Q-tile 128 (4 waves x 32 q), K-tile 64; S^T = K·Q^T (3-pass
// split-bf16), O^T = V^T·P^T (plain bf16).
// ---------------------------------------------------------------------------
__global__ __launch_bounds__(256) void attn_kernel(
    const bf16* __restrict__ Qhi, const bf16* __restrict__ Qlo,
    const bf16* __restrict__ Khg, const bf16* __restrict__ Klg,
    const bf16* __restrict__ Vg, bf16* __restrict__ attnbuf,
    unsigned* __restrict__ ctr)
{
    __shared__ __align__(16) bf16 Khs[64][72];
    __shared__ __align__(16) bf16 Kls[64][72];
    __shared__ __align__(16) bf16 Vt [64][72];   // Vt[d][c]
    __shared__ __align__(16) bf16 Pb [128][72];  // P[q_local][c]
    __shared__ int s_item;

    const int tid  = threadIdx.x;
    const int wave = tid >> 6;
    const int lane = tid & 63;
    const int lm   = lane & 31;
    const int lq2  = lane >> 5;

    const int kr  = tid >> 2;          // K row 0..63
    const int kd0 = (tid & 3) * 16;    // K d-offset
    const int vd  = tid & 63;          // V d (Vt row)
    const int vc0 = (tid >> 6) * 16;   // V c-group

    for (;;) {
        if (tid == 0) s_item = (int)atomicAdd(ctr, 1u);
        __syncthreads();
        const int it = s_item;
        if (it >= N_ITEMS) return;
        const int qt = 15 - (it >> 5);   // heavy tiles first
        const int bh = it & 31;
        const int b = bh >> 4, h = bh & 15;
        const size_t headoff = ((size_t)b * NHEAD + h) * SEQ * HDIM;

        // ---- Q B-fragments in registers (hi/lo), loop-invariant ----
        const int qg = qt * 128 + wave * 32 + lm;
        bf16x8 qh[4], ql[4];
        {
            const bf16* qph = Qhi + headoff + (size_t)qg * HDIM;
            const bf16* qpl = Qlo + headoff + (size_t)qg * HDIM;
#pragma unroll
            for (int c = 0; c < 4; c++) {
                qh[c] = *(const bf16x8*)(qph + c * 16 + lq2 * 8);
                ql[c] = *(const bf16x8*)(qpl + c * 16 + lq2 * 8);
            }
        }

        f32x16 O0, O1;
#pragma unroll
        for (int r = 0; r < 16; r++) { O0[r] = 0.f; O1[r] = 0.f; }
        float m_run = NEGBIG, l_run = 0.f;

        const int ktmax = 2 * qt + 1;
        for (int kt = 0; kt <= ktmax; kt++) {
            // ---- global loads to regs ----
            size_t kbase_g = headoff + (size_t)(kt * 64 + kr) * HDIM + kd0;
            bf16x8 kh0 = *(const bf16x8*)(Khg + kbase_g);
            bf16x8 kh1 = *(const bf16x8*)(Khg + kbase_g + 8);
            bf16x8 kl0 = *(const bf16x8*)(Klg + kbase_g);
            bf16x8 kl1 = *(const bf16x8*)(Klg + kbase_g + 8);
            bf16 vtmp[16];
#pragma unroll
            for (int i = 0; i < 16; i++)
                vtmp[i] = Vg[headoff + (size_t)(kt * 64 + vc0 + i) * HDIM + vd];

            __syncthreads();   // prior iter (or prior item) done reading LDS

            *(bf16x8*)&Khs[kr][kd0]     = kh0;
            *(bf16x8*)&Khs[kr][kd0 + 8] = kh1;
            *(bf16x8*)&Kls[kr][kd0]     = kl0;
            *(bf16x8*)&Kls[kr][kd0 + 8] = kl1;
            {
                bf16x8 v0, v1;
#pragma unroll
                for (int i = 0; i < 8; i++) { v0[i] = vtmp[i]; v1[i] = vtmp[i + 8]; }
                *(bf16x8*)&Vt[vd][vc0]     = v0;
                *(bf16x8*)&Vt[vd][vc0 + 8] = v1;
            }
            __syncthreads();

            // ---- scores: S^T = K · Q^T (hi*hi + hi*lo + lo*hi) ----
            f32x16 s0, s1;
#pragma unroll
            for (int r = 0; r < 16; r++) { s0[r] = 0.f; s1[r] = 0.f; }
#pragma unroll
            for (int c = 0; c < 4; c++) {
                bf16x8 ah0 = *(bf16x8*)&Khs[lm][c * 16 + lq2 * 8];
                bf16x8 al0 = *(bf16x8*)&Kls[lm][c * 16 + lq2 * 8];
                bf16x8 ah1 = *(bf16x8*)&Khs[32 + lm][c * 16 + lq2 * 8];
                bf16x8 al1 = *(bf16x8*)&Kls[32 + lm][c * 16 + lq2 * 8];
                s0 = __builtin_amdgcn_mfma_f32_32x32x16_bf16(ah0, qh[c], s0, 0, 0, 0);
                s0 = __builtin_amdgcn_mfma_f32_32x32x16_bf16(ah0, ql[c], s0, 0, 0, 0);
                s0 = __builtin_amdgcn_mfma_f32_32x32x16_bf16(al0, qh[c], s0, 0, 0, 0);
                s1 = __builtin_amdgcn_mfma_f32_32x32x16_bf16(ah1, qh[c], s1, 0, 0, 0);
                s1 = __builtin_amdgcn_mfma_f32_32x32x16_bf16(ah1, ql[c], s1, 0, 0, 0);
                s1 = __builtin_amdgcn_mfma_f32_32x32x16_bf16(al1, qh[c], s1, 0, 0, 0);
            }

            // ---- logits + causal mask ----
            float logit[2][16];
            const int kbase = kt * 64 + 4 * lq2;
            const bool needmask = (kt * 64 + 63 > qg);
#pragma unroll
            for (int r = 0; r < 16; r++) {
                int koff = (r & 3) + 8 * (r >> 2);
                float L0 = s0[r] * LSCALE;
                float L1 = s1[r] * LSCALE;
                if (needmask) {
                    if (kbase + koff > qg) L0 = NEGBIG;
                    if (kbase + 32 + koff > qg) L1 = NEGBIG;
                }
                logit[0][r] = L0;
                logit[1][r] = L1;
            }

            // ---- online softmax (per-lane scalar state) ----
            float vmax = NEGBIG;
#pragma unroll
            for (int r = 0; r < 16; r++)
                vmax = fmaxf(vmax, fmaxf(logit[0][r], logit[1][r]));
            vmax = fmaxf(vmax, __shfl_xor(vmax, 32, 64));
            float mnew = fmaxf(m_run, vmax);
            float alpha = __expf(m_run - mnew);
            float p[2][16];
            float sum = 0.f;
#pragma unroll
            for (int r = 0; r < 16; r++) {
                p[0][r] = __expf(logit[0][r] - mnew);
                p[1][r] = __expf(logit[1][r] - mnew);
                sum += p[0][r] + p[1][r];
            }
            sum += __shfl_xor(sum, 32, 64);
            l_run = l_run * alpha + sum;
            m_run = mnew;
#pragma unroll
            for (int r = 0; r < 16; r++) { O0[r] *= alpha; O1[r] *= alpha; }

            // ---- write P (bf16) to LDS in natural [q][c] layout ----
#pragma unroll
            for (int mt = 0; mt < 2; mt++)
#pragma unroll
              for (int g = 0; g < 4; g++) {
                bf16x4 pk;
                pk[0] = (bf16)p[mt][4 * g + 0];
                pk[1] = (bf16)p[mt][4 * g + 1];
                pk[2] = (bf16)p[mt][4 * g + 2];
                pk[3] = (bf16)p[mt][4 * g + 3];
                *(bf16x4*)&Pb[wave * 32 + lm][mt * 32 + 8 * g + 4 * lq2] = pk;
              }
            asm volatile("s_waitcnt lgkmcnt(0)" ::: "memory");

            // ---- PV: O^T += V^T · P^T ----
#pragma unroll
            for (int c = 0; c < 4; c++) {
                bf16x8 pb  = *(bf16x8*)&Pb[wave * 32 + lm][c * 16 + lq2 * 8];
                bf16x8 va0 = *(bf16x8*)&Vt[lm][c * 16 + lq2 * 8];
                bf16x8 va1 = *(bf16x8*)&Vt[32 + lm][c * 16 + lq2 * 8];
                O0 = __builtin_amdgcn_mfma_f32_32x32x16_bf16(va0, pb, O0, 0, 0, 0);
                O1 = __builtin_amdgcn_mfma_f32_32x32x16_bf16(va1, pb, O1, 0, 0, 0);
            }
        }

        // ---- epilogue: attnbuf[b][q][h*64+d] = O^T[d][q] / l  (bf16) ----
        const float inv = 1.0f / l_run;
        bf16* orow = attnbuf + ((size_t)b * SEQ + qg) * HID + h * HDIM;
#pragma unroll
        for (int g = 0; g < 4; g++) {
            int d0 = 8 * g + 4 * lq2;
            bf16x4 o0, o1;
#pragma unroll
            for (int i = 0; i < 4; i++) {
                o0[i] = (bf16)(O0[4 * g + i] * inv);
                o1[i] = (bf16)(O1[4 * g + i] * inv);
            }
            *(bf16x4*)(orow + d0)      = o0;
            *(bf16x4*)(orow + 32 + d0) = o1;
        }
    }
}

// ---------------------------------------------------------------------------
// GEMM2 (MFMA, plain bf16): out = attn @ W_out + b_out.
// 128m x 64n tile -> 512 blocks (2/CU), 15.4 KB LDS. Wave w owns m-rows
// [w*32, w*32+32) x all 64 n. Lane owns one output row; float4 stores.
// ---------------------------------------------------------------------------
__global__ __launch_bounds__(256) void gemm_out_mfma(
    const bf16* __restrict__ Attn, const bf16* __restrict__ Wt,
    const float* __restrict__ bias, float* __restrict__ out)
{
    __shared__ __align__(16) bf16 Ah[64][40];    // Wt rows [n][k]
    __shared__ __align__(16) bf16 Bh[128][40];   // attn rows [m][k]

    const int tid = threadIdx.x;
    const int wave = tid >> 6, lane = tid & 63;
    const int lm = lane & 31, lq2 = lane >> 5;
    const int nBase = blockIdx.x * 64;
    const int mBase = blockIdx.y * 128;

    const int sr = tid >> 1, skc = (tid & 1) * 16;   // B staging
    const int ar = tid >> 2, akc = (tid & 3) * 8;    // A staging

    f32x16 acc[2];
#pragma unroll
    for (int nt = 0; nt < 2; nt++)
#pragma unroll
      for (int r = 0; r < 16; r++) acc[nt][r] = 0.f;

    for (int k0 = 0; k0 < HID; k0 += 32) {
        size_t bsrc = (size_t)(mBase + sr) * HID + k0 + skc;
        size_t asrc = (size_t)(nBase + ar) * HID + k0 + akc;
        bf16x8 b0 = *(const bf16x8*)(Attn + bsrc);
        bf16x8 b1 = *(const bf16x8*)(Attn + bsrc + 8);
        bf16x8 a0 = *(const bf16x8*)(Wt + asrc);
        __syncthreads();
        *(bf16x8*)&Bh[sr][skc]     = b0;
        *(bf16x8*)&Bh[sr][skc + 8] = b1;
        *(bf16x8*)&Ah[ar][akc]     = a0;
        __syncthreads();
#pragma unroll
        for (int kh = 0; kh < 2; kh++) {
            const int ko = kh * 16 + lq2 * 8;
            bf16x8 bA  = *(bf16x8*)&Bh[wave * 32 + lm][ko];
            bf16x8 aW0 = *(bf16x8*)&Ah[lm][ko];
            bf16x8 aW1 = *(bf16x8*)&Ah[32 + lm][ko];
            acc[0] = __builtin_amdgcn_mfma_f32_32x32x16_bf16(aW0, bA, acc[0], 0, 0, 0);
            acc[1] = __builtin_amdgcn_mfma_f32_32x32x16_bf16(aW1, bA, acc[1], 0, 0, 0);
        }
    }

    const int m = mBase + wave * 32 + lm;
#pragma unroll
    for (int nt = 0; nt < 2; nt++) {
#pragma unroll
        for (int q4 = 0; q4 < 4; q4++) {
            int n = nBase + nt * 32 + 8 * q4 + 4 * lq2;
            float4 bv = *(const float4*)(bias + n);
            float4 o;
            o.x = acc[nt][q4 * 4 + 0] + bv.x;
            o.y = acc[nt][q4 * 4 + 1] + bv.y;
            o.z = acc[nt][q4 * 4 + 2] + bv.z;
            o.w = acc[nt][q4 * 4 + 3] + bv.w;
            *(float4*)(out + (size_t)m * HID + n) = o;
        }
    }
}

extern "C" void kernel_launch(void* const* d_in, const int* in_sizes, int n_in,
                              void* d_out, int out_size, void* d_ws, size_t ws_size,
                              hipStream_t stream) {
    const float* x    = (const float*)d_in[0];
    const float* Wqkv = (const float*)d_in[1];
    const float* bqkv = (const float*)d_in[2];
    const float* Wout = (const float*)d_in[3];
    const float* bout = (const float*)d_in[4];
    float* out = (float*)d_out;

    // workspace layout (bf16 elements), ~73.4 MB + 4 B.
    // Xhi aliases attnbuf: Xhi is dead after gemm_qkv; attnbuf written later.
    const size_t NW  = (size_t)HID * 3 * HID;              // 3.15M (W_qkv^T)
    const size_t NWo = (size_t)HID * HID;                  // 1.05M
    const size_t NT  = (size_t)BATCH * NHEAD * SEQ * HDIM; // 4.19M per tensor
    bf16* Wthi = (bf16*)d_ws;
    bf16* Wtlo = Wthi + NW;
    bf16* Wot  = Wtlo + NW;
    bf16* qhi  = Wot + NWo;
    bf16* qlo  = qhi + NT;
    bf16* khi  = qlo + NT;
    bf16* klo  = khi + NT;
    bf16* vv   = klo + NT;
    bf16* attnbuf = vv + NT;      // also serves as Xhi (disjoint lifetime)
    bf16* Xhi  = attnbuf;
    bf16* Xlo  = attnbuf + NT;
    unsigned* ctr = (unsigned*)(Xlo + NT);

    // 0) preps: X split (+ queue-counter zero), weight transposes
    xsplit_kernel<<<dim3((BATCH * SEQ * HID) / 1024), 256, 0, stream>>>(x, Xhi, Xlo, ctr);
    transpose_split_kernel<<<dim3(3 * HID / 64, HID / 64), 256, 0, stream>>>(
        Wqkv, Wthi, Wtlo, HID, 3 * HID);
    transpose_split_kernel<<<dim3(HID / 64, HID / 64), 256, 0, stream>>>(
        Wout, Wot, nullptr, HID, HID);
    // 1) QKV projection (split-bf16 MFMA), bf16 split outputs
    gemm_qkv_mfma<<<dim3(3 * HID / 128, BATCH * SEQ / 128), 256, 0, stream>>>(
        Xhi, Xlo, Wthi, Wtlo, bqkv, qhi, qlo, khi, klo, vv);
    // 2) causal flash attention (MFMA), persistent blocks + work queue
    attn_kernel<<<dim3(768), 256, 0, stream>>>(
        qhi, qlo, khi, klo, vv, attnbuf, ctr);
    // 3) output projection (plain bf16 MFMA)
    gemm_out_mfma<<<dim3(HID / 64, BATCH * SEQ / 128), 256, 0, stream>>>(
        attnbuf, Wot, bout, out);
}

// Round 5
// 277.358 us; speedup vs baseline: 1.0768x; 1.0768x over previous
//
#include <hip/hip_runtime.h>
#include <hip/hip_bf16.h>

#define BATCH 2
#define SEQ 2048
#define HID 1024
#define NHEAD 16
#define HDIM 64
// softmax in exp2 domain: logit2 = (q.k) * TEMP_K/sqrt(d) * log2(e)
#define L2SCALE 180.3368800721f
#define NEGBIG (-1.0e30f)
#define N_ITEMS 512   // 16 q-tiles x 32 (b,h)

typedef __bf16 bf16;
typedef __bf16 bf16x4 __attribute__((ext_vector_type(4)));
typedef __bf16 bf16x8 __attribute__((ext_vector_type(8)));
typedef float f32x16 __attribute__((ext_vector_type(16)));

union BQ  { bf16x4 v; unsigned u[2]; };
union BF8 { bf16x8 v; unsigned u[4]; };

// ---------------------------------------------------------------------------
// Prep A: transpose fp32 W[K][N] -> bf16 hi (and optional lo) [N][K].
// ---------------------------------------------------------------------------
__global__ __launch_bounds__(256) void transpose_split_kernel(
    const float* __restrict__ W, bf16* __restrict__ Thi, bf16* __restrict__ Tlo,
    int K, int N)
{
    __shared__ float T[64][65];
    const int tid = threadIdx.x;
    const int kBase = blockIdx.y * 64;
    const int nBase = blockIdx.x * 64;
    {
        const int k0 = tid >> 4;
        const int nc = (tid & 15) * 4;
#pragma unroll
        for (int kk = 0; kk < 4; kk++) {
            int k = k0 + kk * 16;
            float4 v = *(const float4*)(W + (size_t)(kBase + k) * N + nBase + nc);
            T[k][nc] = v.x; T[k][nc + 1] = v.y; T[k][nc + 2] = v.z; T[k][nc + 3] = v.w;
        }
    }
    __syncthreads();
    {
        const int n = tid >> 2;
        const int kc = (tid & 3) * 16;
        bf16x8 h0, h1, l0, l1;
#pragma unroll
        for (int j = 0; j < 8; j++) {
            float a = T[kc + j][n];
            float c = T[kc + 8 + j][n];
            bf16 ha = (bf16)a, hc = (bf16)c;
            h0[j] = ha; h1[j] = hc;
            l0[j] = (bf16)(a - (float)ha);
            l1[j] = (bf16)(c - (float)hc);
        }
        size_t dst = (size_t)(nBase + n) * K + kBase + kc;
        *(bf16x8*)(Thi + dst)     = h0;
        *(bf16x8*)(Thi + dst + 8) = h1;
        if (Tlo) {
            *(bf16x8*)(Tlo + dst)     = l0;
            *(bf16x8*)(Tlo + dst + 8) = l1;
        }
    }
}

// ---------------------------------------------------------------------------
// Prep B: split X fp32 -> Xhi/Xlo bf16; zero the attn work-queue counter.
// ---------------------------------------------------------------------------
__global__ __launch_bounds__(256) void xsplit_kernel(
    const float* __restrict__ X, bf16* __restrict__ Xhi, bf16* __restrict__ Xlo,
    unsigned* __restrict__ ctr)
{
    if (blockIdx.x == 0 && threadIdx.x == 0) *ctr = 0u;
    const int i = blockIdx.x * 256 + threadIdx.x;
    float4 v = ((const float4*)X)[i];
    float xs[4] = {v.x, v.y, v.z, v.w};
    bf16x4 h, l;
#pragma unroll
    for (int j = 0; j < 4; j++) {
        h[j] = (bf16)xs[j];
        l[j] = (bf16)(xs[j] - (float)h[j]);
    }
    ((bf16x4*)Xhi)[i] = h;
    ((bf16x4*)Xlo)[i] = l;
}

// ---------------------------------------------------------------------------
// Prep C: per-head V transpose [b][h][s][d] -> [b][h][d][s] so attention can
// stage V^T with b128 loads (kills the 16x global_load_ushort gather).
// ---------------------------------------------------------------------------
__global__ __launch_bounds__(256) void vtrans_kernel(
    const bf16* __restrict__ vv, bf16* __restrict__ vtr)
{
    __shared__ bf16 T[64][72];
    const int tid = threadIdx.x;
    const int bh = blockIdx.y;
    const int st = blockIdx.x;            // 32 s-tiles of 64
    const int r  = tid >> 2;              // 0..63
    const int c0 = (tid & 3) * 16;
    const bf16* src = vv + ((size_t)bh * SEQ + st * 64) * HDIM;
    bf16x8 a = *(const bf16x8*)(src + (size_t)r * HDIM + c0);
    bf16x8 b = *(const bf16x8*)(src + (size_t)r * HDIM + c0 + 8);
    *(bf16x8*)&T[r][c0]     = a;
    *(bf16x8*)&T[r][c0 + 8] = b;
    __syncthreads();
    bf16x8 o0, o1;
#pragma unroll
    for (int i = 0; i < 8; i++) {
        o0[i] = T[c0 + i][r];
        o1[i] = T[c0 + 8 + i][r];
    }
    bf16* dst = vtr + ((size_t)bh * HDIM + r) * SEQ + st * 64 + c0;
    *(bf16x8*)(dst)     = o0;
    *(bf16x8*)(dst + 8) = o1;
}

// ---------------------------------------------------------------------------
// GEMM1 (MFMA, software-pipelined): qkv = x @ W_qkv + b_qkv, pre-split bf16.
// D^T orientation. Q/K cols: 3-pass split-bf16; V cols: plain bf16.
// Prefetch k0+32 tile into regs during MFMA of k0 (hides vmem latency).
// ---------------------------------------------------------------------------
__global__ __launch_bounds__(256) void gemm_qkv_mfma(
    const bf16* __restrict__ Xhi, const bf16* __restrict__ Xlo,
    const bf16* __restrict__ Wthi, const bf16* __restrict__ Wtlo,
    const float* __restrict__ bias,
    bf16* __restrict__ qhi, bf16* __restrict__ qlo,
    bf16* __restrict__ khi, bf16* __restrict__ klo, bf16* __restrict__ vv)
{
    __shared__ __align__(16) bf16 Xh[128][40];
    __shared__ __align__(16) bf16 Xl[128][40];
    __shared__ __align__(16) bf16 Wh[128][40];
    __shared__ __align__(16) bf16 Wl[128][40];

    const int tid = threadIdx.x;
    const int wave = tid >> 6, lane = tid & 63;
    const int lm = lane & 31, lq2 = lane >> 5;
    const int wave_s = wave & 1, wave_n = wave >> 1;
    const int nBase = blockIdx.x * 128;
    const int sBase = blockIdx.y * 128;
    const bool isV = (nBase >= 2 * HID);

    const int sr = tid >> 1, skc = (tid & 1) * 16;

    f32x16 acc[2][2];
#pragma unroll
    for (int st = 0; st < 2; st++)
#pragma unroll
      for (int nt = 0; nt < 2; nt++)
#pragma unroll
        for (int r = 0; r < 16; r++) acc[st][nt][r] = 0.f;

    bf16x8 cx[2], cw[2], cxl[2] = {}, cwl[2] = {};
    {
        size_t xsrc = (size_t)(sBase + sr) * HID + skc;
        size_t wsrc = (size_t)(nBase + sr) * HID + skc;
        cx[0] = *(const bf16x8*)(Xhi + xsrc);
        cx[1] = *(const bf16x8*)(Xhi + xsrc + 8);
        cw[0] = *(const bf16x8*)(Wthi + wsrc);
        cw[1] = *(const bf16x8*)(Wthi + wsrc + 8);
        if (!isV) {
            cxl[0] = *(const bf16x8*)(Xlo + xsrc);
            cxl[1] = *(const bf16x8*)(Xlo + xsrc + 8);
            cwl[0] = *(const bf16x8*)(Wtlo + wsrc);
            cwl[1] = *(const bf16x8*)(Wtlo + wsrc + 8);
        }
    }

    for (int k0 = 0; k0 < HID; k0 += 32) {
        __syncthreads();
        *(bf16x8*)&Xh[sr][skc]     = cx[0];
        *(bf16x8*)&Xh[sr][skc + 8] = cx[1];
        *(bf16x8*)&Wh[sr][skc]     = cw[0];
        *(bf16x8*)&Wh[sr][skc + 8] = cw[1];
        if (!isV) {
            *(bf16x8*)&Xl[sr][skc]     = cxl[0];
            *(bf16x8*)&Xl[sr][skc + 8] = cxl[1];
            *(bf16x8*)&Wl[sr][skc]     = cwl[0];
            *(bf16x8*)&Wl[sr][skc + 8] = cwl[1];
        }
        __syncthreads();

        // prefetch next k-tile (hidden under MFMA below)
        bf16x8 nx[2] = {}, nw[2] = {}, nxl[2] = {}, nwl[2] = {};
        if (k0 + 32 < HID) {
            size_t xsrc = (size_t)(sBase + sr) * HID + k0 + 32 + skc;
            size_t wsrc = (size_t)(nBase + sr) * HID + k0 + 32 + skc;
            nx[0] = *(const bf16x8*)(Xhi + xsrc);
            nx[1] = *(const bf16x8*)(Xhi + xsrc + 8);
            nw[0] = *(const bf16x8*)(Wthi + wsrc);
            nw[1] = *(const bf16x8*)(Wthi + wsrc + 8);
            if (!isV) {
                nxl[0] = *(const bf16x8*)(Xlo + xsrc);
                nxl[1] = *(const bf16x8*)(Xlo + xsrc + 8);
                nwl[0] = *(const bf16x8*)(Wtlo + wsrc);
                nwl[1] = *(const bf16x8*)(Wtlo + wsrc + 8);
            }
        }

#pragma unroll
        for (int kh = 0; kh < 2; kh++) {
            const int ko = kh * 16 + lq2 * 8;
            bf16x8 aWh[2], aWl[2], bXh[2], bXl[2];
#pragma unroll
            for (int nt = 0; nt < 2; nt++) {
                aWh[nt] = *(bf16x8*)&Wh[wave_n * 64 + nt * 32 + lm][ko];
                if (!isV) aWl[nt] = *(bf16x8*)&Wl[wave_n * 64 + nt * 32 + lm][ko];
            }
#pragma unroll
            for (int st = 0; st < 2; st++) {
                bXh[st] = *(bf16x8*)&Xh[wave_s * 64 + st * 32 + lm][ko];
                if (!isV) bXl[st] = *(bf16x8*)&Xl[wave_s * 64 + st * 32 + lm][ko];
            }
#pragma unroll
            for (int nt = 0; nt < 2; nt++)
#pragma unroll
              for (int st = 0; st < 2; st++) {
                acc[st][nt] = __builtin_amdgcn_mfma_f32_32x32x16_bf16(aWh[nt], bXh[st], acc[st][nt], 0, 0, 0);
                if (!isV) {
                    acc[st][nt] = __builtin_amdgcn_mfma_f32_32x32x16_bf16(aWh[nt], bXl[st], acc[st][nt], 0, 0, 0);
                    acc[st][nt] = __builtin_amdgcn_mfma_f32_32x32x16_bf16(aWl[nt], bXh[st], acc[st][nt], 0, 0, 0);
                }
              }
        }
        cx[0] = nx[0]; cx[1] = nx[1]; cw[0] = nw[0]; cw[1] = nw[1];
        cxl[0] = nxl[0]; cxl[1] = nxl[1]; cwl[0] = nwl[0]; cwl[1] = nwl[1];
    }

#pragma unroll
    for (int st = 0; st < 2; st++) {
        int s = sBase + wave_s * 64 + st * 32 + lm;
        int bb = s >> 11, ss = s & 2047;
#pragma unroll
        for (int nt = 0; nt < 2; nt++) {
#pragma unroll
            for (int q4 = 0; q4 < 4; q4++) {
                int n = nBase + wave_n * 64 + nt * 32 + 8 * q4 + 4 * lq2;
                float4 bv = *(const float4*)(bias + n);
                float vals[4];
                vals[0] = acc[st][nt][q4 * 4 + 0] + bv.x;
                vals[1] = acc[st][nt][q4 * 4 + 1] + bv.y;
                vals[2] = acc[st][nt][q4 * 4 + 2] + bv.z;
                vals[3] = acc[st][nt][q4 * 4 + 3] + bv.w;
                int which = n >> 10, h = (n >> 6) & 15, d = n & 63;
                size_t dst = (((size_t)bb * NHEAD + h) * SEQ + ss) * HDIM + d;
                if (which < 2) {
                    bf16x4 hi4, lo4;
#pragma unroll
                    for (int i = 0; i < 4; i++) {
                        hi4[i] = (bf16)vals[i];
                        lo4[i] = (bf16)(vals[i] - (float)hi4[i]);
                    }
                    bf16* ph = (which == 0) ? qhi : khi;
                    bf16* pl = (which == 0) ? qlo : klo;
                    *(bf16x4*)(ph + dst) = hi4;
                    *(bf16x4*)(pl + dst) = lo4;
                } else {
                    bf16x4 v4;
#pragma unroll
                    for (int i = 0; i < 4; i++) v4[i] = (bf16)vals[i];
                    *(bf16x4*)(vv + dst) = v4;
                }
            }
        }
    }
}

// ---------------------------------------------------------------------------
// MFMA flash attention. Persistent blocks + atomic queue (heavy-first).
// Software-pipelined K/V staging; V^T staged from transposed global layout;
// P handed to PV via shfl_xor(32) register exchange (no LDS round-trip).
// LDS = K hi/lo + V^T only (27.7 KB).
// ---------------------------------------------------------------------------
__global__ __launch_bounds__(256) void attn_kernel(
    const bf16* __restrict__ Qhi, const bf16* __restrict__ Qlo,
    const bf16* __restrict__ Khg, const bf16* __restrict__ Klg,
    const bf16* __restrict__ Vtr, bf16* __restrict__ attnbuf,
    unsigned* __restrict__ ctr)
{
    __shared__ __align__(16) bf16 Khs[64][72];
    __shared__ __align__(16) bf16 Kls[64][72];
    __shared__ __align__(16) bf16 Vt [64][72];   // Vt[d][c]
    __shared__ int s_item;

    const int tid  = threadIdx.x;
    const int wave = tid >> 6;
    const int lane = tid & 63;
    const int lm   = lane & 31;
    const int lq2  = lane >> 5;

    const int kr  = tid >> 2;          // staging row (K: seq-row, V: d-row)
    const int kd0 = (tid & 3) * 16;    // staging col offset

    for (;;) {
        if (tid == 0) s_item = (int)atomicAdd(ctr, 1u);
        __syncthreads();
        const int it = s_item;
        if (it >= N_ITEMS) return;
        const int qt = 15 - (it >> 5);   // heavy tiles first
        const int bh = it & 31;
        const int b = bh >> 4, h = bh & 15;
        const size_t headoff = ((size_t)b * NHEAD + h) * SEQ * HDIM;

        // Q fragments (hi/lo) in registers, loop-invariant
        const int qg = qt * 128 + wave * 32 + lm;
        bf16x8 qh[4], ql[4];
        {
            const bf16* qph = Qhi + headoff + (size_t)qg * HDIM;
            const bf16* qpl = Qlo + headoff + (size_t)qg * HDIM;
#pragma unroll
            for (int c = 0; c < 4; c++) {
                qh[c] = *(const bf16x8*)(qph + c * 16 + lq2 * 8);
                ql[c] = *(const bf16x8*)(qpl + c * 16 + lq2 * 8);
            }
        }

        f32x16 O0, O1;
#pragma unroll
        for (int r = 0; r < 16; r++) { O0[r] = 0.f; O1[r] = 0.f; }
        float m_run = NEGBIG, l_run = 0.f;

        const int ktmax = 2 * qt + 1;
        // prologue load: tile 0
        bf16x8 kc[4], vc[2];
        {
            size_t kg = headoff + (size_t)kr * HDIM + kd0;
            kc[0] = *(const bf16x8*)(Khg + kg);
            kc[1] = *(const bf16x8*)(Khg + kg + 8);
            kc[2] = *(const bf16x8*)(Klg + kg);
            kc[3] = *(const bf16x8*)(Klg + kg + 8);
            size_t vg = headoff + (size_t)kr * SEQ + kd0;
            vc[0] = *(const bf16x8*)(Vtr + vg);
            vc[1] = *(const bf16x8*)(Vtr + vg + 8);
        }

        for (int kt = 0; kt <= ktmax; kt++) {
            __syncthreads();   // prior iteration done reading LDS
            *(bf16x8*)&Khs[kr][kd0]     = kc[0];
            *(bf16x8*)&Khs[kr][kd0 + 8] = kc[1];
            *(bf16x8*)&Kls[kr][kd0]     = kc[2];
            *(bf16x8*)&Kls[kr][kd0 + 8] = kc[3];
            *(bf16x8*)&Vt[kr][kd0]      = vc[0];
            *(bf16x8*)&Vt[kr][kd0 + 8]  = vc[1];
            __syncthreads();

            // prefetch next tile (hidden under compute)
            bf16x8 kn[4], vn[2];
            const bool more = (kt < ktmax);
            if (more) {
                size_t kg = headoff + (size_t)((kt + 1) * 64 + kr) * HDIM + kd0;
                kn[0] = *(const bf16x8*)(Khg + kg);
                kn[1] = *(const bf16x8*)(Khg + kg + 8);
                kn[2] = *(const bf16x8*)(Klg + kg);
                kn[3] = *(const bf16x8*)(Klg + kg + 8);
                size_t vg = headoff + (size_t)kr * SEQ + (kt + 1) * 64 + kd0;
                vn[0] = *(const bf16x8*)(Vtr + vg);
                vn[1] = *(const bf16x8*)(Vtr + vg + 8);
            }

            // wave-uniform skip of fully-masked diagonal waves
            if (kt * 64 <= qt * 128 + wave * 32 + 31) {
                // scores: S^T = K · Q^T (hi*hi + hi*lo + lo*hi)
                f32x16 s[2];
#pragma unroll
                for (int r = 0; r < 16; r++) { s[0][r] = 0.f; s[1][r] = 0.f; }
#pragma unroll
                for (int c = 0; c < 4; c++) {
                    bf16x8 ah0 = *(bf16x8*)&Khs[lm][c * 16 + lq2 * 8];
                    bf16x8 al0 = *(bf16x8*)&Kls[lm][c * 16 + lq2 * 8];
                    bf16x8 ah1 = *(bf16x8*)&Khs[32 + lm][c * 16 + lq2 * 8];
                    bf16x8 al1 = *(bf16x8*)&Kls[32 + lm][c * 16 + lq2 * 8];
                    s[0] = __builtin_amdgcn_mfma_f32_32x32x16_bf16(ah0, qh[c], s[0], 0, 0, 0);
                    s[0] = __builtin_amdgcn_mfma_f32_32x32x16_bf16(ah0, ql[c], s[0], 0, 0, 0);
                    s[0] = __builtin_amdgcn_mfma_f32_32x32x16_bf16(al0, qh[c], s[0], 0, 0, 0);
                    s[1] = __builtin_amdgcn_mfma_f32_32x32x16_bf16(ah1, qh[c], s[1], 0, 0, 0);
                    s[1] = __builtin_amdgcn_mfma_f32_32x32x16_bf16(ah1, ql[c], s[1], 0, 0, 0);
                    s[1] = __builtin_amdgcn_mfma_f32_32x32x16_bf16(al1, qh[c], s[1], 0, 0, 0);
                }

                // logits (exp2 domain) + causal mask, in place
                const int kbase = kt * 64 + 4 * lq2;
                const bool needmask = (kt * 64 + 63 > qg);
#pragma unroll
                for (int mt = 0; mt < 2; mt++)
#pragma unroll
                  for (int r = 0; r < 16; r++) {
                    int koff = (r & 3) + 8 * (r >> 2) + 32 * mt;
                    float L = s[mt][r] * L2SCALE;
                    if (needmask && (kbase + koff > qg)) L = NEGBIG;
                    s[mt][r] = L;
                  }

                // online softmax (per-lane state, one shfl per reduce)
                float vmax = NEGBIG;
#pragma unroll
                for (int r = 0; r < 16; r++)
                    vmax = fmaxf(vmax, fmaxf(s[0][r], s[1][r]));
                vmax = fmaxf(vmax, __shfl_xor(vmax, 32, 64));
                float mnew = fmaxf(m_run, vmax);
                float alpha = exp2f(m_run - mnew);
                float sum = 0.f;
#pragma unroll
                for (int mt = 0; mt < 2; mt++)
#pragma unroll
                  for (int r = 0; r < 16; r++) {
                    s[mt][r] = exp2f(s[mt][r] - mnew);
                    sum += s[mt][r];
                  }
                sum += __shfl_xor(sum, 32, 64);
                l_run = l_run * alpha + sum;
                m_run = mnew;
#pragma unroll
                for (int r = 0; r < 16; r++) { O0[r] *= alpha; O1[r] *= alpha; }

                // build PV B-fragments via lane<->lane^32 exchange
                bf16x8 pfrag[4];
#pragma unroll
                for (int mt = 0; mt < 2; mt++)
#pragma unroll
                  for (int hh = 0; hh < 2; hh++) {
                    BQ A, B;
#pragma unroll
                    for (int i = 0; i < 4; i++) {
                        A.v[i] = (bf16)s[mt][8 * hh + i];
                        B.v[i] = (bf16)s[mt][8 * hh + 4 + i];
                    }
                    unsigned s0_ = lq2 ? A.u[0] : B.u[0];
                    unsigned s1_ = lq2 ? A.u[1] : B.u[1];
                    unsigned r0 = __shfl_xor(s0_, 32, 64);
                    unsigned r1 = __shfl_xor(s1_, 32, 64);
                    BF8 f;
                    f.u[0] = lq2 ? r0 : A.u[0];
                    f.u[1] = lq2 ? r1 : A.u[1];
                    f.u[2] = lq2 ? B.u[0] : r0;
                    f.u[3] = lq2 ? B.u[1] : r1;
                    pfrag[mt * 2 + hh] = f.v;
                  }

                // PV: O^T += V^T · P^T
#pragma unroll
                for (int c = 0; c < 4; c++) {
                    bf16x8 va0 = *(bf16x8*)&Vt[lm][c * 16 + lq2 * 8];
                    bf16x8 va1 = *(bf16x8*)&Vt[32 + lm][c * 16 + lq2 * 8];
                    O0 = __builtin_amdgcn_mfma_f32_32x32x16_bf16(va0, pfrag[c], O0, 0, 0, 0);
                    O1 = __builtin_amdgcn_mfma_f32_32x32x16_bf16(va1, pfrag[c], O1, 0, 0, 0);
                }
            }

            if (more) {
#pragma unroll
                for (int i = 0; i < 4; i++) kc[i] = kn[i];
                vc[0] = vn[0]; vc[1] = vn[1];
            }
        }

        // epilogue: attnbuf[b][q][h*64+d] = O^T[d][q] / l  (bf16)
        const float inv = 1.0f / l_run;
        bf16* orow = attnbuf + ((size_t)b * SEQ + qg) * HID + h * HDIM;
#pragma unroll
        for (int g = 0; g < 4; g++) {
            int d0 = 8 * g + 4 * lq2;
            bf16x4 o0, o1;
#pragma unroll
            for (int i = 0; i < 4; i++) {
                o0[i] = (bf16)(O0[4 * g + i] * inv);
                o1[i] = (bf16)(O1[4 * g + i] * inv);
            }
            *(bf16x4*)(orow + d0)      = o0;
            *(bf16x4*)(orow + 32 + d0) = o1;
        }
    }
}

// ---------------------------------------------------------------------------
// GEMM2 (MFMA, plain bf16, pipelined): out = attn @ W_out + b_out.
// 128m x 64n tile -> 512 blocks, 15.4 KB LDS.
// ---------------------------------------------------------------------------
__global__ __launch_bounds__(256) void gemm_out_mfma(
    const bf16* __restrict__ Attn, const bf16* __restrict__ Wt,
    const float* __restrict__ bias, float* __restrict__ out)
{
    __shared__ __align__(16) bf16 Ah[64][40];    // Wt rows [n][k]
    __shared__ __align__(16) bf16 Bh[128][40];   // attn rows [m][k]

    const int tid = threadIdx.x;
    const int wave = tid >> 6, lane = tid & 63;
    const int lm = lane & 31, lq2 = lane >> 5;
    const int nBase = blockIdx.x * 64;
    const int mBase = blockIdx.y * 128;

    const int sr = tid >> 1, skc = (tid & 1) * 16;
    const int ar = tid >> 2, akc = (tid & 3) * 8;

    f32x16 acc[2];
#pragma unroll
    for (int nt = 0; nt < 2; nt++)
#pragma unroll
      for (int r = 0; r < 16; r++) acc[nt][r] = 0.f;

    bf16x8 cb[2], ca;
    {
        cb[0] = *(const bf16x8*)(Attn + (size_t)(mBase + sr) * HID + skc);
        cb[1] = *(const bf16x8*)(Attn + (size_t)(mBase + sr) * HID + skc + 8);
        ca    = *(const bf16x8*)(Wt + (size_t)(nBase + ar) * HID + akc);
    }

    for (int k0 = 0; k0 < HID; k0 += 32) {
        __syncthreads();
        *(bf16x8*)&Bh[sr][skc]     = cb[0];
        *(bf16x8*)&Bh[sr][skc + 8] = cb[1];
        *(bf16x8*)&Ah[ar][akc]     = ca;
        __syncthreads();

        bf16x8 nb[2] = {}, na = {};
        if (k0 + 32 < HID) {
            nb[0] = *(const bf16x8*)(Attn + (size_t)(mBase + sr) * HID + k0 + 32 + skc);
            nb[1] = *(const bf16x8*)(Attn + (size_t)(mBase + sr) * HID + k0 + 32 + skc + 8);
            na    = *(const bf16x8*)(Wt + (size_t)(nBase + ar) * HID + k0 + 32 + akc);
        }
#pragma unroll
        for (int kh = 0; kh < 2; kh++) {
            const int ko = kh * 16 + lq2 * 8;
            bf16x8 bA  = *(bf16x8*)&Bh[wave * 32 + lm][ko];
            bf16x8 aW0 = *(bf16x8*)&Ah[lm][ko];
            bf16x8 aW1 = *(bf16x8*)&Ah[32 + lm][ko];
            acc[0] = __builtin_amdgcn_mfma_f32_32x32x16_bf16(aW0, bA, acc[0], 0, 0, 0);
            acc[1] = __builtin_amdgcn_mfma_f32_32x32x16_bf16(aW1, bA, acc[1], 0, 0, 0);
        }
        cb[0] = nb[0]; cb[1] = nb[1]; ca = na;
    }

    const int m = mBase + wave * 32 + lm;
#pragma unroll
    for (int nt = 0; nt < 2; nt++) {
#pragma unroll
        for (int q4 = 0; q4 < 4; q4++) {
            int n = nBase + nt * 32 + 8 * q4 + 4 * lq2;
            float4 bv = *(const float4*)(bias + n);
            float4 o;
            o.x = acc[nt][q4 * 4 + 0] + bv.x;
            o.y = acc[nt][q4 * 4 + 1] + bv.y;
            o.z = acc[nt][q4 * 4 + 2] + bv.z;
            o.w = acc[nt][q4 * 4 + 3] + bv.w;
            *(float4*)(out + (size_t)m * HID + n) = o;
        }
    }
}

extern "C" void kernel_launch(void* const* d_in, const int* in_sizes, int n_in,
                              void* d_out, int out_size, void* d_ws, size_t ws_size,
                              hipStream_t stream) {
    const float* x    = (const float*)d_in[0];
    const float* Wqkv = (const float*)d_in[1];
    const float* bqkv = (const float*)d_in[2];
    const float* Wout = (const float*)d_in[3];
    const float* bout = (const float*)d_in[4];
    float* out = (float*)d_out;

    // workspace (bf16 elements), ~73.4 MB + 4 B. Aliases (disjoint lifetimes):
    //   Xhi == attnbuf   (Xhi dead after gemm_qkv; attnbuf written by attn)
    //   Xlo == vtr       (Xlo dead after gemm_qkv; vtr written by vtrans)
    const size_t NW  = (size_t)HID * 3 * HID;
    const size_t NWo = (size_t)HID * HID;
    const size_t NT  = (size_t)BATCH * NHEAD * SEQ * HDIM;
    bf16* Wthi = (bf16*)d_ws;
    bf16* Wtlo = Wthi + NW;
    bf16* Wot  = Wtlo + NW;
    bf16* qhi  = Wot + NWo;
    bf16* qlo  = qhi + NT;
    bf16* khi  = qlo + NT;
    bf16* klo  = khi + NT;
    bf16* vv   = klo + NT;
    bf16* attnbuf = vv + NT;
    bf16* Xhi  = attnbuf;
    bf16* Xlo  = attnbuf + NT;
    bf16* vtr  = Xlo;
    unsigned* ctr = (unsigned*)(Xlo + NT);

    xsplit_kernel<<<dim3((BATCH * SEQ * HID) / 1024), 256, 0, stream>>>(x, Xhi, Xlo, ctr);
    transpose_split_kernel<<<dim3(3 * HID / 64, HID / 64), 256, 0, stream>>>(
        Wqkv, Wthi, Wtlo, HID, 3 * HID);
    transpose_split_kernel<<<dim3(HID / 64, HID / 64), 256, 0, stream>>>(
        Wout, Wot, nullptr, HID, HID);
    gemm_qkv_mfma<<<dim3(3 * HID / 128, BATCH * SEQ / 128), 256, 0, stream>>>(
        Xhi, Xlo, Wthi, Wtlo, bqkv, qhi, qlo, khi, klo, vv);
    vtrans_kernel<<<dim3(SEQ / 64, BATCH * NHEAD), 256, 0, stream>>>(vv, vtr);
    attn_kernel<<<dim3(1024), 256, 0, stream>>>(
        qhi, qlo, khi, klo, vtr, attnbuf, ctr);
    gemm_out_mfma<<<dim3(HID / 64, BATCH * SEQ / 128), 256, 0, stream>>>(
        attnbuf, Wot, bout, out);
}

// Round 6
// 254.281 us; speedup vs baseline: 1.1745x; 1.0908x over previous
//
#include <hip/hip_runtime.h>
#include <hip/hip_bf16.h>

#define BATCH 2
#define SEQ 2048
#define HID 1024
#define NHEAD 16
#define HDIM 64
// softmax in exp2 domain: logit2 = (q.k) * TEMP_K/sqrt(d) * log2(e)
#define L2SCALE 180.3368800721f
#define NEGBIG (-1.0e30f)

typedef __bf16 bf16;
typedef __bf16 bf16x4 __attribute__((ext_vector_type(4)));
typedef __bf16 bf16x8 __attribute__((ext_vector_type(8)));
typedef float f32x16 __attribute__((ext_vector_type(16)));

union BQ  { bf16x4 v; unsigned u[2]; };
union BF8 { bf16x8 v; unsigned u[4]; };

// Split-K item table (heavy-first). Each item: (qt, first k-tile, #k-tiles,
// partial-slot or -1 for single-chunk/full-range items).
__device__ __constant__ int TAB_QT[30]  = {5,6,7,8,9,10,11,11,12,12,13,13,14,14,15,15, 4,10, 3,9,15, 2,8,14, 1,7,13, 0,6,12};
__device__ __constant__ int TAB_K0[30]  = {0,0,0,0,0,0,0,12,0,12,0,12,0,12,0,12, 0,12, 0,12,24, 0,12,24, 0,12,24, 0,12,24};
__device__ __constant__ int TAB_NIT[30] = {12,12,12,12,12,12,12,12,12,12,12,12,12,12,12,12, 10,10, 8,8,8, 6,6,6, 4,4,4, 2,2,2};
__device__ __constant__ int TAB_PID[30] = {-1,0,2,4,6,8,10,11,12,13,15,16,18,19,21,22, -1,9, -1,7,23, -1,5,20, -1,3,17, -1,1,14};

// ---------------------------------------------------------------------------
// Prep A: transpose fp32 W[K][N] -> bf16 hi (and optional lo) [N][K].
// ---------------------------------------------------------------------------
__global__ __launch_bounds__(256) void transpose_split_kernel(
    const float* __restrict__ W, bf16* __restrict__ Thi, bf16* __restrict__ Tlo,
    int K, int N)
{
    __shared__ float T[64][65];
    const int tid = threadIdx.x;
    const int kBase = blockIdx.y * 64;
    const int nBase = blockIdx.x * 64;
    {
        const int k0 = tid >> 4;
        const int nc = (tid & 15) * 4;
#pragma unroll
        for (int kk = 0; kk < 4; kk++) {
            int k = k0 + kk * 16;
            float4 v = *(const float4*)(W + (size_t)(kBase + k) * N + nBase + nc);
            T[k][nc] = v.x; T[k][nc + 1] = v.y; T[k][nc + 2] = v.z; T[k][nc + 3] = v.w;
        }
    }
    __syncthreads();
    {
        const int n = tid >> 2;
        const int kc = (tid & 3) * 16;
        bf16x8 h0, h1, l0, l1;
#pragma unroll
        for (int j = 0; j < 8; j++) {
            float a = T[kc + j][n];
            float c = T[kc + 8 + j][n];
            bf16 ha = (bf16)a, hc = (bf16)c;
            h0[j] = ha; h1[j] = hc;
            l0[j] = (bf16)(a - (float)ha);
            l1[j] = (bf16)(c - (float)hc);
        }
        size_t dst = (size_t)(nBase + n) * K + kBase + kc;
        *(bf16x8*)(Thi + dst)     = h0;
        *(bf16x8*)(Thi + dst + 8) = h1;
        if (Tlo) {
            *(bf16x8*)(Tlo + dst)     = l0;
            *(bf16x8*)(Tlo + dst + 8) = l1;
        }
    }
}

// ---------------------------------------------------------------------------
// Prep B: split X fp32 -> Xhi/Xlo bf16 (elementwise).
// ---------------------------------------------------------------------------
__global__ __launch_bounds__(256) void xsplit_kernel(
    const float* __restrict__ X, bf16* __restrict__ Xhi, bf16* __restrict__ Xlo)
{
    const int i = blockIdx.x * 256 + threadIdx.x;
    float4 v = ((const float4*)X)[i];
    float xs[4] = {v.x, v.y, v.z, v.w};
    bf16x4 h, l;
#pragma unroll
    for (int j = 0; j < 4; j++) {
        h[j] = (bf16)xs[j];
        l[j] = (bf16)(xs[j] - (float)h[j]);
    }
    ((bf16x4*)Xhi)[i] = h;
    ((bf16x4*)Xlo)[i] = l;
}

// ---------------------------------------------------------------------------
// Prep C: per-head V transpose [b][h][s][d] -> [b][h][d][s].
// ---------------------------------------------------------------------------
__global__ __launch_bounds__(256) void vtrans_kernel(
    const bf16* __restrict__ vv, bf16* __restrict__ vtr)
{
    __shared__ bf16 T[64][72];
    const int tid = threadIdx.x;
    const int bh = blockIdx.y;
    const int st = blockIdx.x;
    const int r  = tid >> 2;
    const int c0 = (tid & 3) * 16;
    const bf16* src = vv + ((size_t)bh * SEQ + st * 64) * HDIM;
    bf16x8 a = *(const bf16x8*)(src + (size_t)r * HDIM + c0);
    bf16x8 b = *(const bf16x8*)(src + (size_t)r * HDIM + c0 + 8);
    *(bf16x8*)&T[r][c0]     = a;
    *(bf16x8*)&T[r][c0 + 8] = b;
    __syncthreads();
    bf16x8 o0, o1;
#pragma unroll
    for (int i = 0; i < 8; i++) {
        o0[i] = T[c0 + i][r];
        o1[i] = T[c0 + 8 + i][r];
    }
    bf16* dst = vtr + ((size_t)bh * HDIM + r) * SEQ + st * 64 + c0;
    *(bf16x8*)(dst)     = o0;
    *(bf16x8*)(dst + 8) = o1;
}

// ---------------------------------------------------------------------------
// GEMM1 (MFMA, pipelined): qkv = x @ W_qkv + b_qkv, pre-split bf16.
// (unchanged from round 5)
// ---------------------------------------------------------------------------
__global__ __launch_bounds__(256) void gemm_qkv_mfma(
    const bf16* __restrict__ Xhi, const bf16* __restrict__ Xlo,
    const bf16* __restrict__ Wthi, const bf16* __restrict__ Wtlo,
    const float* __restrict__ bias,
    bf16* __restrict__ qhi, bf16* __restrict__ qlo,
    bf16* __restrict__ khi, bf16* __restrict__ klo, bf16* __restrict__ vv)
{
    __shared__ __align__(16) bf16 Xh[128][40];
    __shared__ __align__(16) bf16 Xl[128][40];
    __shared__ __align__(16) bf16 Wh[128][40];
    __shared__ __align__(16) bf16 Wl[128][40];

    const int tid = threadIdx.x;
    const int wave = tid >> 6, lane = tid & 63;
    const int lm = lane & 31, lq2 = lane >> 5;
    const int wave_s = wave & 1, wave_n = wave >> 1;
    const int nBase = blockIdx.x * 128;
    const int sBase = blockIdx.y * 128;
    const bool isV = (nBase >= 2 * HID);

    const int sr = tid >> 1, skc = (tid & 1) * 16;

    f32x16 acc[2][2];
#pragma unroll
    for (int st = 0; st < 2; st++)
#pragma unroll
      for (int nt = 0; nt < 2; nt++)
#pragma unroll
        for (int r = 0; r < 16; r++) acc[st][nt][r] = 0.f;

    bf16x8 cx[2], cw[2], cxl[2] = {}, cwl[2] = {};
    {
        size_t xsrc = (size_t)(sBase + sr) * HID + skc;
        size_t wsrc = (size_t)(nBase + sr) * HID + skc;
        cx[0] = *(const bf16x8*)(Xhi + xsrc);
        cx[1] = *(const bf16x8*)(Xhi + xsrc + 8);
        cw[0] = *(const bf16x8*)(Wthi + wsrc);
        cw[1] = *(const bf16x8*)(Wthi + wsrc + 8);
        if (!isV) {
            cxl[0] = *(const bf16x8*)(Xlo + xsrc);
            cxl[1] = *(const bf16x8*)(Xlo + xsrc + 8);
            cwl[0] = *(const bf16x8*)(Wtlo + wsrc);
            cwl[1] = *(const bf16x8*)(Wtlo + wsrc + 8);
        }
    }

    for (int k0 = 0; k0 < HID; k0 += 32) {
        __syncthreads();
        *(bf16x8*)&Xh[sr][skc]     = cx[0];
        *(bf16x8*)&Xh[sr][skc + 8] = cx[1];
        *(bf16x8*)&Wh[sr][skc]     = cw[0];
        *(bf16x8*)&Wh[sr][skc + 8] = cw[1];
        if (!isV) {
            *(bf16x8*)&Xl[sr][skc]     = cxl[0];
            *(bf16x8*)&Xl[sr][skc + 8] = cxl[1];
            *(bf16x8*)&Wl[sr][skc]     = cwl[0];
            *(bf16x8*)&Wl[sr][skc + 8] = cwl[1];
        }
        __syncthreads();

        bf16x8 nx[2] = {}, nw[2] = {}, nxl[2] = {}, nwl[2] = {};
        if (k0 + 32 < HID) {
            size_t xsrc = (size_t)(sBase + sr) * HID + k0 + 32 + skc;
            size_t wsrc = (size_t)(nBase + sr) * HID + k0 + 32 + skc;
            nx[0] = *(const bf16x8*)(Xhi + xsrc);
            nx[1] = *(const bf16x8*)(Xhi + xsrc + 8);
            nw[0] = *(const bf16x8*)(Wthi + wsrc);
            nw[1] = *(const bf16x8*)(Wthi + wsrc + 8);
            if (!isV) {
                nxl[0] = *(const bf16x8*)(Xlo + xsrc);
                nxl[1] = *(const bf16x8*)(Xlo + xsrc + 8);
                nwl[0] = *(const bf16x8*)(Wtlo + wsrc);
                nwl[1] = *(const bf16x8*)(Wtlo + wsrc + 8);
            }
        }

#pragma unroll
        for (int kh = 0; kh < 2; kh++) {
            const int ko = kh * 16 + lq2 * 8;
            bf16x8 aWh[2], aWl[2], bXh[2], bXl[2];
#pragma unroll
            for (int nt = 0; nt < 2; nt++) {
                aWh[nt] = *(bf16x8*)&Wh[wave_n * 64 + nt * 32 + lm][ko];
                if (!isV) aWl[nt] = *(bf16x8*)&Wl[wave_n * 64 + nt * 32 + lm][ko];
            }
#pragma unroll
            for (int st = 0; st < 2; st++) {
                bXh[st] = *(bf16x8*)&Xh[wave_s * 64 + st * 32 + lm][ko];
                if (!isV) bXl[st] = *(bf16x8*)&Xl[wave_s * 64 + st * 32 + lm][ko];
            }
#pragma unroll
            for (int nt = 0; nt < 2; nt++)
#pragma unroll
              for (int st = 0; st < 2; st++) {
                acc[st][nt] = __builtin_amdgcn_mfma_f32_32x32x16_bf16(aWh[nt], bXh[st], acc[st][nt], 0, 0, 0);
                if (!isV) {
                    acc[st][nt] = __builtin_amdgcn_mfma_f32_32x32x16_bf16(aWh[nt], bXl[st], acc[st][nt], 0, 0, 0);
                    acc[st][nt] = __builtin_amdgcn_mfma_f32_32x32x16_bf16(aWl[nt], bXh[st], acc[st][nt], 0, 0, 0);
                }
              }
        }
        cx[0] = nx[0]; cx[1] = nx[1]; cw[0] = nw[0]; cw[1] = nw[1];
        cxl[0] = nxl[0]; cxl[1] = nxl[1]; cwl[0] = nwl[0]; cwl[1] = nwl[1];
    }

#pragma unroll
    for (int st = 0; st < 2; st++) {
        int s = sBase + wave_s * 64 + st * 32 + lm;
        int bb = s >> 11, ss = s & 2047;
#pragma unroll
        for (int nt = 0; nt < 2; nt++) {
#pragma unroll
            for (int q4 = 0; q4 < 4; q4++) {
                int n = nBase + wave_n * 64 + nt * 32 + 8 * q4 + 4 * lq2;
                float4 bv = *(const float4*)(bias + n);
                float vals[4];
                vals[0] = acc[st][nt][q4 * 4 + 0] + bv.x;
                vals[1] = acc[st][nt][q4 * 4 + 1] + bv.y;
                vals[2] = acc[st][nt][q4 * 4 + 2] + bv.z;
                vals[3] = acc[st][nt][q4 * 4 + 3] + bv.w;
                int which = n >> 10, h = (n >> 6) & 15, d = n & 63;
                size_t dst = (((size_t)bb * NHEAD + h) * SEQ + ss) * HDIM + d;
                if (which < 2) {
                    bf16x4 hi4, lo4;
#pragma unroll
                    for (int i = 0; i < 4; i++) {
                        hi4[i] = (bf16)vals[i];
                        lo4[i] = (bf16)(vals[i] - (float)hi4[i]);
                    }
                    bf16* ph = (which == 0) ? qhi : khi;
                    bf16* pl = (which == 0) ? qlo : klo;
                    *(bf16x4*)(ph + dst) = hi4;
                    *(bf16x4*)(pl + dst) = lo4;
                } else {
                    bf16x4 v4;
#pragma unroll
                    for (int i = 0; i < 4; i++) v4[i] = (bf16)vals[i];
                    *(bf16x4*)(vv + dst) = v4;
                }
            }
        }
    }
}

// ---------------------------------------------------------------------------
// MFMA flash attention, SPLIT-K: 960 near-uniform items (qt, k-chunk <=12
// k-tiles, bh), static heavy-first grid -> ~4 blocks/CU resident throughout.
// Single-chunk items (qt<=5) write final attnbuf; multi-chunk items write
// bf16 O-partials + fp32 (m,l) for the combine kernel.
// ---------------------------------------------------------------------------
__global__ __launch_bounds__(256) void attn_kernel(
    const bf16* __restrict__ Qhi, const bf16* __restrict__ Qlo,
    const bf16* __restrict__ Khg, const bf16* __restrict__ Klg,
    const bf16* __restrict__ Vtr, bf16* __restrict__ attnbuf,
    bf16* __restrict__ PartO, float* __restrict__ Mls)
{
    __shared__ __align__(16) bf16 Khs[64][72];
    __shared__ __align__(16) bf16 Kls[64][72];
    __shared__ __align__(16) bf16 Vt [64][72];   // Vt[d][c]

    const int tid  = threadIdx.x;
    const int wave = tid >> 6;
    const int lane = tid & 63;
    const int lm   = lane & 31;
    const int lq2  = lane >> 5;

    const int kr  = tid >> 2;
    const int kd0 = (tid & 3) * 16;

    const int slot = blockIdx.x >> 5;
    const int bh   = blockIdx.x & 31;
    const int qt   = TAB_QT[slot];
    const int kt0  = TAB_K0[slot];
    const int nit  = TAB_NIT[slot];
    const int pid  = TAB_PID[slot];
    const int b = bh >> 4, h = bh & 15;
    const size_t headoff = ((size_t)b * NHEAD + h) * SEQ * HDIM;

    // Q fragments (hi/lo) in registers, loop-invariant
    const int ql_loc = wave * 32 + lm;         // q within tile
    const int qg = qt * 128 + ql_loc;          // global q
    bf16x8 qh[4], qlr[4];
    {
        const bf16* qph = Qhi + headoff + (size_t)qg * HDIM;
        const bf16* qpl = Qlo + headoff + (size_t)qg * HDIM;
#pragma unroll
        for (int c = 0; c < 4; c++) {
            qh[c]  = *(const bf16x8*)(qph + c * 16 + lq2 * 8);
            qlr[c] = *(const bf16x8*)(qpl + c * 16 + lq2 * 8);
        }
    }

    f32x16 O0, O1;
#pragma unroll
    for (int r = 0; r < 16; r++) { O0[r] = 0.f; O1[r] = 0.f; }
    float m_run = NEGBIG, l_run = 0.f;

    const int wave_qmin = qt * 128 + wave * 32;
    const int ktend = kt0 + nit;

    // prologue load: first tile of the chunk
    bf16x8 kc[4], vc[2];
    {
        size_t kg = headoff + (size_t)(kt0 * 64 + kr) * HDIM + kd0;
        kc[0] = *(const bf16x8*)(Khg + kg);
        kc[1] = *(const bf16x8*)(Khg + kg + 8);
        kc[2] = *(const bf16x8*)(Klg + kg);
        kc[3] = *(const bf16x8*)(Klg + kg + 8);
        size_t vg = headoff + (size_t)kr * SEQ + kt0 * 64 + kd0;
        vc[0] = *(const bf16x8*)(Vtr + vg);
        vc[1] = *(const bf16x8*)(Vtr + vg + 8);
    }

    for (int kt = kt0; kt < ktend; kt++) {
        __syncthreads();
        *(bf16x8*)&Khs[kr][kd0]     = kc[0];
        *(bf16x8*)&Khs[kr][kd0 + 8] = kc[1];
        *(bf16x8*)&Kls[kr][kd0]     = kc[2];
        *(bf16x8*)&Kls[kr][kd0 + 8] = kc[3];
        *(bf16x8*)&Vt[kr][kd0]      = vc[0];
        *(bf16x8*)&Vt[kr][kd0 + 8]  = vc[1];
        __syncthreads();

        // prefetch next tile
        bf16x8 kn[4], vn[2];
        const bool more = (kt + 1 < ktend);
        if (more) {
            size_t kg = headoff + (size_t)((kt + 1) * 64 + kr) * HDIM + kd0;
            kn[0] = *(const bf16x8*)(Khg + kg);
            kn[1] = *(const bf16x8*)(Khg + kg + 8);
            kn[2] = *(const bf16x8*)(Klg + kg);
            kn[3] = *(const bf16x8*)(Klg + kg + 8);
            size_t vg = headoff + (size_t)kr * SEQ + (kt + 1) * 64 + kd0;
            vn[0] = *(const bf16x8*)(Vtr + vg);
            vn[1] = *(const bf16x8*)(Vtr + vg + 8);
        }

        // wave-uniform skip of fully-masked k-tiles
        if (kt * 64 <= wave_qmin + 31) {
            // scores: S^T = K · Q^T (hi*hi + hi*lo + lo*hi)
            f32x16 s[2];
#pragma unroll
            for (int r = 0; r < 16; r++) { s[0][r] = 0.f; s[1][r] = 0.f; }
#pragma unroll
            for (int c = 0; c < 4; c++) {
                bf16x8 ah0 = *(bf16x8*)&Khs[lm][c * 16 + lq2 * 8];
                bf16x8 al0 = *(bf16x8*)&Kls[lm][c * 16 + lq2 * 8];
                bf16x8 ah1 = *(bf16x8*)&Khs[32 + lm][c * 16 + lq2 * 8];
                bf16x8 al1 = *(bf16x8*)&Kls[32 + lm][c * 16 + lq2 * 8];
                s[0] = __builtin_amdgcn_mfma_f32_32x32x16_bf16(ah0, qh[c],  s[0], 0, 0, 0);
                s[0] = __builtin_amdgcn_mfma_f32_32x32x16_bf16(ah0, qlr[c], s[0], 0, 0, 0);
                s[0] = __builtin_amdgcn_mfma_f32_32x32x16_bf16(al0, qh[c],  s[0], 0, 0, 0);
                s[1] = __builtin_amdgcn_mfma_f32_32x32x16_bf16(ah1, qh[c],  s[1], 0, 0, 0);
                s[1] = __builtin_amdgcn_mfma_f32_32x32x16_bf16(ah1, qlr[c], s[1], 0, 0, 0);
                s[1] = __builtin_amdgcn_mfma_f32_32x32x16_bf16(al1, qh[c],  s[1], 0, 0, 0);
            }

            // logits (exp2 domain); mask only when this k-tile can overlap
            // the diagonal for some lane of this wave (wave-uniform branch)
            if (kt * 64 + 63 > wave_qmin) {
                const int kbase = kt * 64 + 4 * lq2;
#pragma unroll
                for (int mt = 0; mt < 2; mt++)
#pragma unroll
                  for (int r = 0; r < 16; r++) {
                    int koff = (r & 3) + 8 * (r >> 2) + 32 * mt;
                    float L = s[mt][r] * L2SCALE;
                    if (kbase + koff > qg) L = NEGBIG;
                    s[mt][r] = L;
                  }
            } else {
#pragma unroll
                for (int mt = 0; mt < 2; mt++)
#pragma unroll
                  for (int r = 0; r < 16; r++) s[mt][r] *= L2SCALE;
            }

            // online softmax (per-lane state)
            float vmax = NEGBIG;
#pragma unroll
            for (int r = 0; r < 16; r++)
                vmax = fmaxf(vmax, fmaxf(s[0][r], s[1][r]));
            vmax = fmaxf(vmax, __shfl_xor(vmax, 32, 64));
            float mnew = fmaxf(m_run, vmax);
            float alpha = exp2f(m_run - mnew);
            float sum = 0.f;
#pragma unroll
            for (int mt = 0; mt < 2; mt++)
#pragma unroll
              for (int r = 0; r < 16; r++) {
                s[mt][r] = exp2f(s[mt][r] - mnew);
                sum += s[mt][r];
              }
            sum += __shfl_xor(sum, 32, 64);
            l_run = l_run * alpha + sum;
            m_run = mnew;
#pragma unroll
            for (int r = 0; r < 16; r++) { O0[r] *= alpha; O1[r] *= alpha; }

            // PV B-fragments via lane<->lane^32 exchange
            bf16x8 pfrag[4];
#pragma unroll
            for (int mt = 0; mt < 2; mt++)
#pragma unroll
              for (int hh = 0; hh < 2; hh++) {
                BQ A, B;
#pragma unroll
                for (int i = 0; i < 4; i++) {
                    A.v[i] = (bf16)s[mt][8 * hh + i];
                    B.v[i] = (bf16)s[mt][8 * hh + 4 + i];
                }
                unsigned s0_ = lq2 ? A.u[0] : B.u[0];
                unsigned s1_ = lq2 ? A.u[1] : B.u[1];
                unsigned r0 = __shfl_xor(s0_, 32, 64);
                unsigned r1 = __shfl_xor(s1_, 32, 64);
                BF8 f;
                f.u[0] = lq2 ? r0 : A.u[0];
                f.u[1] = lq2 ? r1 : A.u[1];
                f.u[2] = lq2 ? B.u[0] : r0;
                f.u[3] = lq2 ? B.u[1] : r1;
                pfrag[mt * 2 + hh] = f.v;
              }

            // PV: O^T += V^T · P^T
#pragma unroll
            for (int c = 0; c < 4; c++) {
                bf16x8 va0 = *(bf16x8*)&Vt[lm][c * 16 + lq2 * 8];
                bf16x8 va1 = *(bf16x8*)&Vt[32 + lm][c * 16 + lq2 * 8];
                O0 = __builtin_amdgcn_mfma_f32_32x32x16_bf16(va0, pfrag[c], O0, 0, 0, 0);
                O1 = __builtin_amdgcn_mfma_f32_32x32x16_bf16(va1, pfrag[c], O1, 0, 0, 0);
            }
        }

        if (more) {
#pragma unroll
            for (int i = 0; i < 4; i++) kc[i] = kn[i];
            vc[0] = vn[0]; vc[1] = vn[1];
        }
    }

    if (pid < 0) {
        // single-chunk: finalize
        const float inv = 1.0f / l_run;
        bf16* orow = attnbuf + ((size_t)b * SEQ + qg) * HID + h * HDIM;
#pragma unroll
        for (int g = 0; g < 4; g++) {
            int d0 = 8 * g + 4 * lq2;
            bf16x4 o0, o1;
#pragma unroll
            for (int i = 0; i < 4; i++) {
                o0[i] = (bf16)(O0[4 * g + i] * inv);
                o1[i] = (bf16)(O1[4 * g + i] * inv);
            }
            *(bf16x4*)(orow + d0)      = o0;
            *(bf16x4*)(orow + 32 + d0) = o1;
        }
    } else {
        // multi-chunk: write bf16 O-partial + (m,l)
        bf16* prow = PartO + (((size_t)pid * 32 + bh) * 128 + ql_loc) * HDIM;
#pragma unroll
        for (int g = 0; g < 4; g++) {
            int d0 = 8 * g + 4 * lq2;
            bf16x4 o0, o1;
#pragma unroll
            for (int i = 0; i < 4; i++) {
                o0[i] = (bf16)O0[4 * g + i];
                o1[i] = (bf16)O1[4 * g + i];
            }
            *(bf16x4*)(prow + d0)      = o0;
            *(bf16x4*)(prow + 32 + d0) = o1;
        }
        if (lq2 == 0) {
            float2 ml = make_float2(m_run, l_run);
            *(float2*)&Mls[(((size_t)pid * 32 + bh) * 128 + ql_loc) * 2] = ml;
        }
    }
}

// ---------------------------------------------------------------------------
// Combine pass: merge 2-3 chunk partials per (qt>=6, bh) via online-softmax
// weights, write final bf16 attnbuf rows.
// ---------------------------------------------------------------------------
__global__ __launch_bounds__(256) void attn_combine(
    const bf16* __restrict__ PartO, const float* __restrict__ Mls,
    bf16* __restrict__ attnbuf)
{
    const int tid = threadIdx.x;
    const int qt = 6 + blockIdx.x / 32;
    const int bh = blockIdx.x & 31;
    const int b = bh >> 4, h = bh & 15;
    const int qrow = tid >> 1;            // 0..127
    const int dh = (tid & 1) * 32;

    int pid0, nch;
    if (qt < 12) { pid0 = 2 * (qt - 6); nch = 2; }
    else         { pid0 = 12 + 3 * (qt - 12); nch = 3; }

    float mv[3], lv[3];
    float M = NEGBIG;
#pragma unroll
    for (int c = 0; c < 3; c++) {
        if (c < nch) {
            float2 ml = *(const float2*)&Mls[(((size_t)(pid0 + c) * 32 + bh) * 128 + qrow) * 2];
            mv[c] = ml.x; lv[c] = ml.y;
            M = fmaxf(M, mv[c]);
        }
    }
    float L = 0.f;
    float acc[32];
#pragma unroll
    for (int i = 0; i < 32; i++) acc[i] = 0.f;
#pragma unroll
    for (int c = 0; c < 3; c++) {
        if (c < nch) {
            float w = exp2f(mv[c] - M);
            L += w * lv[c];
            const bf16* p = PartO + (((size_t)(pid0 + c) * 32 + bh) * 128 + qrow) * HDIM + dh;
#pragma unroll
            for (int g = 0; g < 4; g++) {
                bf16x8 v = *(const bf16x8*)(p + g * 8);
#pragma unroll
                for (int i = 0; i < 8; i++) acc[g * 8 + i] += w * (float)v[i];
            }
        }
    }
    const float inv = 1.0f / L;
    bf16* orow = attnbuf + ((size_t)b * SEQ + qt * 128 + qrow) * HID + h * HDIM + dh;
#pragma unroll
    for (int g = 0; g < 4; g++) {
        bf16x8 o;
#pragma unroll
        for (int i = 0; i < 8; i++) o[i] = (bf16)(acc[g * 8 + i] * inv);
        *(bf16x8*)(orow + g * 8) = o;
    }
}

// ---------------------------------------------------------------------------
// GEMM2 (MFMA, plain bf16, pipelined): out = attn @ W_out + b_out.
// ---------------------------------------------------------------------------
__global__ __launch_bounds__(256) void gemm_out_mfma(
    const bf16* __restrict__ Attn, const bf16* __restrict__ Wt,
    const float* __restrict__ bias, float* __restrict__ out)
{
    __shared__ __align__(16) bf16 Ah[64][40];
    __shared__ __align__(16) bf16 Bh[128][40];

    const int tid = threadIdx.x;
    const int wave = tid >> 6, lane = tid & 63;
    const int lm = lane & 31, lq2 = lane >> 5;
    const int nBase = blockIdx.x * 64;
    const int mBase = blockIdx.y * 128;

    const int sr = tid >> 1, skc = (tid & 1) * 16;
    const int ar = tid >> 2, akc = (tid & 3) * 8;

    f32x16 acc[2];
#pragma unroll
    for (int nt = 0; nt < 2; nt++)
#pragma unroll
      for (int r = 0; r < 16; r++) acc[nt][r] = 0.f;

    bf16x8 cb[2], ca;
    {
        cb[0] = *(const bf16x8*)(Attn + (size_t)(mBase + sr) * HID + skc);
        cb[1] = *(const bf16x8*)(Attn + (size_t)(mBase + sr) * HID + skc + 8);
        ca    = *(const bf16x8*)(Wt + (size_t)(nBase + ar) * HID + akc);
    }

    for (int k0 = 0; k0 < HID; k0 += 32) {
        __syncthreads();
        *(bf16x8*)&Bh[sr][skc]     = cb[0];
        *(bf16x8*)&Bh[sr][skc + 8] = cb[1];
        *(bf16x8*)&Ah[ar][akc]     = ca;
        __syncthreads();

        bf16x8 nb[2] = {}, na = {};
        if (k0 + 32 < HID) {
            nb[0] = *(const bf16x8*)(Attn + (size_t)(mBase + sr) * HID + k0 + 32 + skc);
            nb[1] = *(const bf16x8*)(Attn + (size_t)(mBase + sr) * HID + k0 + 32 + skc + 8);
            na    = *(const bf16x8*)(Wt + (size_t)(nBase + ar) * HID + k0 + 32 + akc);
        }
#pragma unroll
        for (int kh = 0; kh < 2; kh++) {
            const int ko = kh * 16 + lq2 * 8;
            bf16x8 bA  = *(bf16x8*)&Bh[wave * 32 + lm][ko];
            bf16x8 aW0 = *(bf16x8*)&Ah[lm][ko];
            bf16x8 aW1 = *(bf16x8*)&Ah[32 + lm][ko];
            acc[0] = __builtin_amdgcn_mfma_f32_32x32x16_bf16(aW0, bA, acc[0], 0, 0, 0);
            acc[1] = __builtin_amdgcn_mfma_f32_32x32x16_bf16(aW1, bA, acc[1], 0, 0, 0);
        }
        cb[0] = nb[0]; cb[1] = nb[1]; ca = na;
    }

    const int m = mBase + wave * 32 + lm;
#pragma unroll
    for (int nt = 0; nt < 2; nt++) {
#pragma unroll
        for (int q4 = 0; q4 < 4; q4++) {
            int n = nBase + nt * 32 + 8 * q4 + 4 * lq2;
            float4 bv = *(const float4*)(bias + n);
            float4 o;
            o.x = acc[nt][q4 * 4 + 0] + bv.x;
            o.y = acc[nt][q4 * 4 + 1] + bv.y;
            o.z = acc[nt][q4 * 4 + 2] + bv.z;
            o.w = acc[nt][q4 * 4 + 3] + bv.w;
            *(float4*)(out + (size_t)m * HID + n) = o;
        }
    }
}

extern "C" void kernel_launch(void* const* d_in, const int* in_sizes, int n_in,
                              void* d_out, int out_size, void* d_ws, size_t ws_size,
                              hipStream_t stream) {
    const float* x    = (const float*)d_in[0];
    const float* Wqkv = (const float*)d_in[1];
    const float* bqkv = (const float*)d_in[2];
    const float* Wout = (const float*)d_in[3];
    const float* bout = (const float*)d_in[4];
    float* out = (float*)d_out;

    // workspace (bf16 elements), ~73.4 MB (same as round 5). Aliases:
    //   Xhi == attnbuf      (Xhi dead after gemm_qkv)
    //   Xlo == vtr          (Xlo dead after gemm_qkv)
    //   PartO == Wthi+Wtlo  (weights dead after gemm_qkv; 24 pids x 32 bh x
    //                        128q x 64d bf16 = 12.58 MB = exactly 2*NW elems)
    //   Mls == vv           (vv dead after vtrans; 768 x 128 x 2 f32)
    const size_t NW  = (size_t)HID * 3 * HID;
    const size_t NWo = (size_t)HID * HID;
    const size_t NT  = (size_t)BATCH * NHEAD * SEQ * HDIM;
    bf16* Wthi = (bf16*)d_ws;
    bf16* Wtlo = Wthi + NW;
    bf16* Wot  = Wtlo + NW;
    bf16* qhi  = Wot + NWo;
    bf16* qlo  = qhi + NT;
    bf16* khi  = qlo + NT;
    bf16* klo  = khi + NT;
    bf16* vv   = klo + NT;
    bf16* attnbuf = vv + NT;
    bf16* Xhi  = attnbuf;
    bf16* Xlo  = attnbuf + NT;
    bf16* vtr  = Xlo;
    bf16* PartO = Wthi;
    float* Mls  = (float*)vv;

    xsplit_kernel<<<dim3((BATCH * SEQ * HID) / 1024), 256, 0, stream>>>(x, Xhi, Xlo);
    transpose_split_kernel<<<dim3(3 * HID / 64, HID / 64), 256, 0, stream>>>(
        Wqkv, Wthi, Wtlo, HID, 3 * HID);
    transpose_split_kernel<<<dim3(HID / 64, HID / 64), 256, 0, stream>>>(
        Wout, Wot, nullptr, HID, HID);
    gemm_qkv_mfma<<<dim3(3 * HID / 128, BATCH * SEQ / 128), 256, 0, stream>>>(
        Xhi, Xlo, Wthi, Wtlo, bqkv, qhi, qlo, khi, klo, vv);
    vtrans_kernel<<<dim3(SEQ / 64, BATCH * NHEAD), 256, 0, stream>>>(vv, vtr);
    // split-K attention: 30 slots x 32 (b,h) = 960 uniform-ish items
    attn_kernel<<<dim3(960), 256, 0, stream>>>(
        qhi, qlo, khi, klo, vtr, attnbuf, PartO, Mls);
    // combine partials for qt>=6 (320 blocks)
    attn_combine<<<dim3(320), 256, 0, stream>>>(PartO, Mls, attnbuf);
    gemm_out_mfma<<<dim3(HID / 64, BATCH * SEQ / 128), 256, 0, stream>>>(
        attnbuf, Wot, bout, out);
}